// Round 4
// baseline (6607.365 us; speedup 1.0000x reference)
//
#include <hip/hip_runtime.h>
#include <hip/hip_fp16.h>

#define N_USERS 100000
#define M_ITEMS 50000
#define N_NODES 150000
#define N_EDGES 6000000
#define DIM 64

#define VAL_BITS 14
#define VAL_MASK ((1u << VAL_BITS) - 1u)                  // 16383
#define VAL_SCALE 16383.0f
#define VAL_INV   (1.0f / 16383.0f)

#define NPB     128                                       // nodes per dst-bucket (pow2)
#define N_BKT2  1172                                      // ceil(150000/128); 5 blk/CU -> co-resident
#define NBIN    37                                        // src>>12 bins (4096 rows = 512 KB window)

#define P_BLK   256                                       // partition blocks
#define PT      512                                       // threads for count/scatter
#define CHUNK   ((N_EDGES + P_BLK - 1) / P_BLK)           // 23438 edges per block

// ---- init: h_cur(fp16) = concat(user_emb, item_emb) ----------------------------
__global__ void init_kernel(const float4* __restrict__ user_emb,
                            const float4* __restrict__ item_emb,
                            ushort4* __restrict__ h_cur) {
    const int n_user4 = N_USERS * DIM / 4;
    const int n_tot4  = N_NODES * DIM / 4;
    int i = blockIdx.x * blockDim.x + threadIdx.x;
    if (i < n_tot4) {
        float4 v = (i < n_user4) ? user_emb[i] : item_emb[i - n_user4];
        ushort4 hv;
        hv.x = __half_as_ushort(__float2half_rn(v.x));
        hv.y = __half_as_ushort(__float2half_rn(v.y));
        hv.z = __half_as_ushort(__float2half_rn(v.z));
        hv.w = __half_as_ushort(__float2half_rn(v.w));
        h_cur[i] = hv;
    }
}

// ---- pass 1: per-(block,bucket) histogram via LDS ------------------------------
__global__ __launch_bounds__(PT) void count_kernel(const int* __restrict__ dst,
                                                   int* __restrict__ cnt) {  // [P_BLK][N_BKT2]
    __shared__ int hist[N_BKT2];
    int p = blockIdx.x, tid = threadIdx.x;
    for (int i = tid; i < N_BKT2; i += PT) hist[i] = 0;
    __syncthreads();
    int beg = p * CHUNK;
    int end = min(beg + CHUNK, N_EDGES);
    for (int e = beg + tid; e < end; e += PT) {
        unsigned int d = (unsigned int)__builtin_nontemporal_load(&dst[e]);
        atomicAdd(&hist[d >> 7], 1);
    }
    __syncthreads();
    for (int i = tid; i < N_BKT2; i += PT) cnt[p * N_BKT2 + i] = hist[i];
}

// ---- per-bucket exclusive scan over blocks (in place); emit bucket totals ------
__global__ __launch_bounds__(P_BLK) void colscan_kernel(int* __restrict__ cnt,     // [P_BLK][N_BKT2]
                                                        int* __restrict__ totals) {// [N_BKT2]
    __shared__ int lds[P_BLK];
    int b = blockIdx.x, tid = threadIdx.x;
    int v = cnt[tid * N_BKT2 + b];
    lds[tid] = v;
    __syncthreads();
    for (int off = 1; off < P_BLK; off <<= 1) {
        int t = (tid >= off) ? lds[tid - off] : 0;
        __syncthreads();
        lds[tid] += t;
        __syncthreads();
    }
    cnt[tid * N_BKT2 + b] = lds[tid] - v;                 // exclusive within bucket
    if (tid == P_BLK - 1) totals[b] = lds[P_BLK - 1];
}

// ---- exclusive scan of 1172 bucket totals -> bucket_base; one block, 2/thread --
__global__ __launch_bounds__(1024) void bucket_scan_kernel(const int* __restrict__ totals,
                                                           int* __restrict__ bucket_base) {
    __shared__ int lds[1024];
    int t = threadIdx.x;
    int i0 = 2 * t, i1 = 2 * t + 1;
    int a = (i0 < N_BKT2) ? totals[i0] : 0;
    int b = (i1 < N_BKT2) ? totals[i1] : 0;
    int s = a + b;
    lds[t] = s;
    __syncthreads();
    for (int off = 1; off < 1024; off <<= 1) {
        int x = (t >= off) ? lds[t - off] : 0;
        __syncthreads();
        lds[t] += x;
        __syncthreads();
    }
    int excl = lds[t] - s;
    if (i0 < N_BKT2) bucket_base[i0] = excl;
    if (i1 < N_BKT2) bucket_base[i1] = excl + a;
    if (t == 0) bucket_base[N_BKT2] = N_EDGES;
}

// ---- pass 2: deterministic scatter into private contiguous (block,bucket) runs -
// payload = (src << 14) | round(val * 16383)
__global__ __launch_bounds__(PT) void scatter_kernel(const int* __restrict__ src,
                                                     const int* __restrict__ dst,
                                                     const float* __restrict__ val,
                                                     const int* __restrict__ bucket_base,
                                                     const int* __restrict__ cnt,
                                                     uint2* __restrict__ bucketed) {
    __shared__ int lofs[N_BKT2];
    int p = blockIdx.x, tid = threadIdx.x;
    for (int i = tid; i < N_BKT2; i += PT)
        lofs[i] = bucket_base[i] + cnt[p * N_BKT2 + i];
    __syncthreads();
    int beg = p * CHUNK;
    int end = min(beg + CHUNK, N_EDGES);
    for (int e = beg + tid; e < end; e += PT) {
        unsigned int d = (unsigned int)__builtin_nontemporal_load(&dst[e]);
        int s = __builtin_nontemporal_load(&src[e]);
        float w = __builtin_nontemporal_load(&val[e]);
        unsigned int q = __float2uint_rn(w * VAL_SCALE);
        unsigned int payload = ((unsigned int)s << VAL_BITS) | q;
        int pos = atomicAdd(&lofs[d >> 7], 1);            // LDS atomic only
        bucketed[pos] = make_uint2(d, payload);
    }
}

// ---- per-bucket 37-bin counting sort by src_hi -> (pay, loc) split arrays ------
__global__ __launch_bounds__(256) void sort_kernel(const uint2* __restrict__ bucketed,
                                                   const int* __restrict__ bucket_base,
                                                   unsigned int* __restrict__ csr_pay,
                                                   unsigned char* __restrict__ csr_loc) {
    __shared__ int histo[NBIN];
    __shared__ int cur[NBIN];
    int tid = threadIdx.x, b = blockIdx.x;
    int node0 = b << 7;
    int rbeg = bucket_base[b];
    int rend = bucket_base[b + 1];
    if (tid < NBIN) histo[tid] = 0;
    __syncthreads();
    for (int i = rbeg + tid; i < rend; i += 256) {
        uint2 e = bucketed[i];
        atomicAdd(&histo[e.y >> 26], 1);                  // src>>12 = payload>>26
    }
    __syncthreads();
    if (tid == 0) {
        int run = 0;
        for (int i = 0; i < NBIN; ++i) { cur[i] = run; run += histo[i]; }
    }
    __syncthreads();
    for (int i = rbeg + tid; i < rend; i += 256) {
        uint2 e = bucketed[i];
        int pos = rbeg + atomicAdd(&cur[e.y >> 26], 1);
        csr_pay[pos] = e.y;
        csr_loc[pos] = (unsigned char)(e.x - (unsigned int)node0);
    }
}

// ---- convoy SpMM: one co-resident block per 128-node bucket; src-sorted edges;
//      wave-uniform edges: 1 coalesced 128B row load + 1 ds_add_f32 per edge ----
__global__ __launch_bounds__(256, 5) void spmm_conv(const int* __restrict__ bucket_base,
                                                    const unsigned int* __restrict__ pay,
                                                    const unsigned char* __restrict__ loc,
                                                    const __half* __restrict__ h_in,
                                                    __half* __restrict__ h_out,
                                                    const __half* __restrict__ h1,
                                                    const float* __restrict__ user_emb,
                                                    const float* __restrict__ item_emb,
                                                    float* __restrict__ out,
                                                    int last) {
    __shared__ float accs[NPB * DIM];                     // 32 KB -> 5 blocks/CU
    int tid  = threadIdx.x;
    int w    = tid >> 6;
    int lane = tid & 63;
    int b = blockIdx.x;
    int node0 = b << 7;

    for (int i = tid; i < NPB * DIM; i += 256) accs[i] = 0.f;
    __syncthreads();

    int rbeg = bucket_base[b];
    int rend = bucket_base[b + 1];

    // 4 waves striped at 64-edge batches: aligned src sweep within the block
    int e0 = rbeg + w * 64;
    for (; e0 + 64 <= rend; e0 += 256) {
        unsigned int vpay = pay[e0 + lane];               // coalesced dword
        int vloc = (int)loc[e0 + lane];                   // coalesced byte
        #pragma unroll
        for (int i = 0; i < 64; ++i) {
            unsigned int p = (unsigned int)__builtin_amdgcn_readlane((int)vpay, i);
            int slot = __builtin_amdgcn_readlane(vloc, i);
            float ww = (float)(p & VAL_MASK) * VAL_INV;
            float hv = __half2float(h_in[(size_t)(p >> VAL_BITS) * DIM + lane]);
            atomicAdd(&accs[slot * DIM + lane], ww * hv);
        }
    }
    if (e0 < rend) {                                      // tail (< 64 edges)
        int valid = rend - e0;
        unsigned int vpay = (lane < valid) ? pay[e0 + lane] : 0u;
        int vloc = (lane < valid) ? (int)loc[e0 + lane] : 0;
        #pragma unroll 1
        for (int i = 0; i < valid; ++i) {
            unsigned int p = (unsigned int)__builtin_amdgcn_readlane((int)vpay, i);
            int slot = __builtin_amdgcn_readlane(vloc, i);
            float ww = (float)(p & VAL_MASK) * VAL_INV;
            float hv = __half2float(h_in[(size_t)(p >> VAL_BITS) * DIM + lane]);
            atomicAdd(&accs[slot * DIM + lane], ww * hv);
        }
    }
    __syncthreads();

    // epilogue: stream bucket rows out, coalesced
    int nb = min(NPB, N_NODES - node0);
    if (!last) {
        for (int q = tid; q < nb * 8; q += 256) {         // 8 halfs per item
            int n = q >> 3, c = q & 7;
            const float* a = &accs[n * DIM + c * 8];
            __half2 h0 = __floats2half2_rn(a[0], a[1]);
            __half2 h1v = __floats2half2_rn(a[2], a[3]);
            __half2 h2 = __floats2half2_rn(a[4], a[5]);
            __half2 h3 = __floats2half2_rn(a[6], a[7]);
            uint4 w4;
            w4.x = *(const unsigned int*)&h0;
            w4.y = *(const unsigned int*)&h1v;
            w4.z = *(const unsigned int*)&h2;
            w4.w = *(const unsigned int*)&h3;
            *(uint4*)(h_out + (size_t)(node0 + n) * DIM + (size_t)c * 8) = w4;
        }
    } else {
        for (int q = tid; q < nb * 8; q += 256) {         // 8 floats per item
            int n = q >> 3, c = q & 7;
            int node = node0 + n;
            size_t o = (size_t)node * DIM + (size_t)c * 8;
            const float* a = &accs[n * DIM + c * 8];
            uint4 a1 = *(const uint4*)(h1 + o);           // h1 row chunk (8 halfs)
            uint4 a2 = *(const uint4*)(h_in + o);         // h2 row chunk
            const float* ebase = (node < N_USERS) ? (user_emb + o)
                                                  : (item_emb + (o - (size_t)N_USERS * DIM));
            float4 e0v = ((const float4*)ebase)[0];
            float4 e1v = ((const float4*)ebase)[1];
            float2 b0 = __half22float2(*(const __half2*)&a1.x);
            float2 b1 = __half22float2(*(const __half2*)&a1.y);
            float2 b2 = __half22float2(*(const __half2*)&a1.z);
            float2 b3 = __half22float2(*(const __half2*)&a1.w);
            float2 c0 = __half22float2(*(const __half2*)&a2.x);
            float2 c1 = __half22float2(*(const __half2*)&a2.y);
            float2 c2 = __half22float2(*(const __half2*)&a2.z);
            float2 c3 = __half22float2(*(const __half2*)&a2.w);
            float4 x0, x1;
            x0.x = (e0v.x + b0.x + c0.x + a[0]) * 0.25f;
            x0.y = (e0v.y + b0.y + c0.y + a[1]) * 0.25f;
            x0.z = (e0v.z + b1.x + c1.x + a[2]) * 0.25f;
            x0.w = (e0v.w + b1.y + c1.y + a[3]) * 0.25f;
            x1.x = (e1v.x + b2.x + c2.x + a[4]) * 0.25f;
            x1.y = (e1v.y + b2.y + c2.y + a[5]) * 0.25f;
            x1.z = (e1v.z + b3.x + c3.x + a[6]) * 0.25f;
            x1.w = (e1v.w + b3.y + c3.y + a[7]) * 0.25f;
            float4* op = (float4*)(out + o);
            op[0] = x0;
            op[1] = x1;
        }
    }
}

extern "C" void kernel_launch(void* const* d_in, const int* in_sizes, int n_in,
                              void* d_out, int out_size, void* d_ws, size_t ws_size,
                              hipStream_t stream) {
    const float* user_emb = (const float*)d_in[0];
    const float* item_emb = (const float*)d_in[1];
    const int*   edge_src = (const int*)d_in[2];
    const int*   edge_dst = (const int*)d_in[3];
    const float* edge_val = (const float*)d_in[4];
    float* out = (float*)d_out;

    // ---- workspace layout ----
    char* p = (char*)d_ws;
    __half* h_a = (__half*)p;                  p += (size_t)N_NODES * DIM * 2;        // 19.2 MB
    unsigned int* csr_pay = (unsigned int*)p;  p += (size_t)(N_EDGES + 256) * 4;      // 24 MB (+pad)
    unsigned char* csr_loc = (unsigned char*)p;p += (size_t)(N_EDGES + 1024);         // 6 MB (+pad)
    int* bucket_base = (int*)p;                p += (size_t)(N_BKT2 + 16) * 4;
    int* totals = (int*)p;                     p += (size_t)(N_BKT2 + 16) * 4;
    int* cnt = (int*)p;                        p += (size_t)P_BLK * N_BKT2 * 4;       // 1.2 MB
    // union region: bucketed (build phase, 48 MB) / h_b (pull phase, 19.2 MB)
    uint2*  bucketed = (uint2*)p;
    __half* h_b      = (__half*)p;

    const int n4 = N_NODES * DIM / 4;
    const int ew_blocks = (n4 + 255) / 256;

    // ---- build bucketed + src-sorted edge lists (no global atomics) ----
    init_kernel<<<ew_blocks, 256, 0, stream>>>((const float4*)user_emb,
                                               (const float4*)item_emb,
                                               (ushort4*)h_a);
    count_kernel<<<P_BLK, PT, 0, stream>>>(edge_dst, cnt);
    colscan_kernel<<<N_BKT2, P_BLK, 0, stream>>>(cnt, totals);
    bucket_scan_kernel<<<1, 1024, 0, stream>>>(totals, bucket_base);
    scatter_kernel<<<P_BLK, PT, 0, stream>>>(edge_src, edge_dst, edge_val,
                                             bucket_base, cnt, bucketed);
    sort_kernel<<<N_BKT2, 256, 0, stream>>>(bucketed, bucket_base, csr_pay, csr_loc);

    // ---- 3 convoy layers; acc deferred into layer-3 epilogue ----
    // L1: h_a(h0) -> h_b(h1);  L2: h_b(h1) -> h_a(h2);  L3: h_a(h2) -> out
    spmm_conv<<<N_BKT2, 256, 0, stream>>>(bucket_base, csr_pay, csr_loc, h_a, h_b,
                                          h_b, user_emb, item_emb, out, 0);
    spmm_conv<<<N_BKT2, 256, 0, stream>>>(bucket_base, csr_pay, csr_loc, h_b, h_a,
                                          h_b, user_emb, item_emb, out, 0);
    spmm_conv<<<N_BKT2, 256, 0, stream>>>(bucket_base, csr_pay, csr_loc, h_a, h_b,
                                          h_b, user_emb, item_emb, out, 1);
}